// Round 2
// baseline (8769.119 us; speedup 1.0000x reference)
//
#include <hip/hip_runtime.h>
#include <hip/hip_bf16.h>
#include <cstdint>
#include <cmath>

typedef unsigned short u16;
typedef unsigned int u32;

// ---- model dims ----
#define B_    8
#define T_IN  2048
#define CIN1  273
#define L1_   1025
#define L_    513
#define C_    512
#define CE_   576
#define M1_   (B_*L1_)   /* 8200 */
#define M_    (B_*L_)    /* 4104 */
#define K1_   (CIN1*4)   /* 1092 */
#define H_    8
#define D_    64
#define R_    50

// ======================= generic GEMM: C[m,n] = sum_k A[m,k]*B[n,k] + bias =======================
// amode: 0 = fp32 row-major A (lda), 2 = conv1 im2col from meg (fp32), 3 = conv2 im2col from x1 (fp32)
// cmode: 0 = fp32 C[m*ldc+n], 1 = fp32 out at [b][n][t] (m = b*L_+t), n<128
__device__ __forceinline__ float a_load(const void* A, int m, int k, int lda, int amode) {
    if (amode == 0) {
        return ((const float*)A)[(size_t)m * lda + k];
    } else if (amode == 2) {
        int b = m / L1_, t = m - b * L1_;
        int ci = k >> 2, kk = k & 3;
        int it = 2 * t - 2 + kk;
        if ((unsigned)it >= (unsigned)T_IN) return 0.f;
        return ((const float*)A)[((size_t)(b * CIN1 + ci)) * T_IN + it];
    } else {
        int b = m / L_, t = m - b * L_;
        int ci = k >> 2, kk = k & 3;
        int it = 2 * t - 2 + kk;
        if ((unsigned)it >= (unsigned)L1_) return 0.f;
        return ((const float*)A)[((size_t)(b * L1_ + it)) * C_ + ci];
    }
}

__global__ __launch_bounds__(256) void gemm_kernel(
    const void* __restrict__ Aptr, const float* __restrict__ Bptr,
    const float* __restrict__ bias1, const float* __restrict__ bias2,
    float* __restrict__ Cf,
    int Msz, int Nsz, int Ksz, int lda, int ldc, int amode, int cmode, int relu)
{
    __shared__ float As[16][68];
    __shared__ float Bs[16][68];
    int tid = threadIdx.x;
    int tx = tid & 15, ty = tid >> 4;      // compute: n-group, m-group
    int kq = tid & 15, mq = tid >> 4;      // load: k, m/n row
    int m0 = blockIdx.x * 64, n0 = blockIdx.y * 64;

    float acc[4][4];
#pragma unroll
    for (int i = 0; i < 4; ++i)
#pragma unroll
        for (int j = 0; j < 4; ++j) acc[i][j] = 0.f;

    for (int k0 = 0; k0 < Ksz; k0 += 16) {
        int k = k0 + kq;
#pragma unroll
        for (int j = 0; j < 4; ++j) {
            int rl = mq + 16 * j;
            // A tile
            int m = m0 + rl;
            float av = 0.f;
            if (m < Msz && k < Ksz) av = a_load(Aptr, m, k, lda, amode);
            As[kq][rl] = av;
            // B tile (fp32 weights, row n of length Ksz)
            float bv = 0.f;
            if (k < Ksz) bv = Bptr[(size_t)(n0 + rl) * Ksz + k];
            Bs[kq][rl] = bv;
        }
        __syncthreads();
#pragma unroll
        for (int kk = 0; kk < 16; ++kk) {
            float a4[4], b4[4];
            *(float4*)a4 = *(const float4*)&As[kk][ty * 4];
            *(float4*)b4 = *(const float4*)&Bs[kk][tx * 4];
#pragma unroll
            for (int i = 0; i < 4; ++i)
#pragma unroll
                for (int j = 0; j < 4; ++j) acc[i][j] += a4[i] * b4[j];
        }
        __syncthreads();
    }

#pragma unroll
    for (int i = 0; i < 4; ++i) {
        int m = m0 + ty * 4 + i;
        if (m >= Msz) continue;
#pragma unroll
        for (int j = 0; j < 4; ++j) {
            int n = n0 + tx * 4 + j;
            float v = acc[i][j] + bias1[n] + (bias2 ? bias2[n] : 0.f);
            if (relu) v = fmaxf(v, 0.f);
            if (cmode == 0) {
                Cf[(size_t)m * ldc + n] = v;
            } else {
                int b = m / L_, t = m - b * L_;
                Cf[((size_t)(b * 128 + n)) * L_ + t] = v;
            }
        }
    }
}

// ======================= subject embedding concat =======================
__global__ __launch_bounds__(256) void emb_kernel(const float* __restrict__ semb,
                                                  const int* __restrict__ subj,
                                                  float* __restrict__ x2bt)
{
    int idx = blockIdx.x * 256 + threadIdx.x;
    if (idx >= M_ * 64) return;
    int m = idx >> 6, e = idx & 63;
    int b = m / L_;
    x2bt[(size_t)m * CE_ + 512 + e] = semb[subj[b] * 64 + e];
}

// ======================= W_hh transpose-pack: fp32 [2048][512] -> float2 [256 c-pairs][2048] =======================
__global__ __launch_bounds__(256) void pack_whh(const float2* __restrict__ Wsrc, float2* __restrict__ Wdst)
{
    __shared__ float2 tile[32][33];
    int bx = blockIdx.x;   // gate-row block (2048/32)
    int by = blockIdx.y;   // c2 block (256/32)
    int tid = threadIdx.x;
    int lx = tid & 31, ly = tid >> 5;
#pragma unroll
    for (int i = 0; i < 4; ++i) {
        int gj = bx * 32 + ly + i * 8;
        int c2 = by * 32 + lx;
        tile[ly + i * 8][lx] = Wsrc[(size_t)gj * 256 + c2];
    }
    __syncthreads();
#pragma unroll
    for (int i = 0; i < 4; ++i) {
        int c2 = by * 32 + ly + i * 8;
        int gj = bx * 32 + lx;
        Wdst[(size_t)c2 * 2048 + gj] = tile[lx][ly + i * 8];
    }
}

// ======================= LSTM step (one timestep, all batches) =======================
// grid 128 = 8 batches x 16 j-chunks(32). pre[(b*L+t)*2048 + gate*512 + j] already has x*Wih + bih + bhh.
__global__ __launch_bounds__(256) void lstm_step(const float* __restrict__ pre,
                                                 const float2* __restrict__ W2,
                                                 float* __restrict__ hseq,
                                                 float* __restrict__ cstate, int t)
{
    int b = blockIdx.x >> 4;
    int jc = blockIdx.x & 15;
    int tid = threadIdx.x;
    int j_loc = tid & 31, g = (tid >> 5) & 3, cs = tid >> 7;
    int j = jc * 32 + j_loc;

    __shared__ float hprev[512];
    __shared__ float part[2][4][32];

    const float* hsrc = hseq + (size_t)(b * L_ + (t - 1)) * C_;
    for (int i = tid; i < 512; i += 256) hprev[i] = (t == 0) ? 0.f : hsrc[i];
    __syncthreads();

    float acc = 0.f;
    const float2* wp = W2 + (size_t)(cs * 128) * 2048 + (g * 512 + j);
    const float* hp = hprev + cs * 256;
#pragma unroll 8
    for (int i = 0; i < 128; ++i) {
        float2 u = wp[(size_t)i * 2048];
        acc += u.x * hp[2 * i] + u.y * hp[2 * i + 1];
    }
    part[cs][g][j_loc] = acc;
    __syncthreads();

    if (tid < 32) {
        int jj = jc * 32 + tid;
        const float* pr = pre + (size_t)(b * L_ + t) * 2048;
        float gi = pr[jj]          + part[0][0][tid] + part[1][0][tid];
        float gf = pr[512 + jj]    + part[0][1][tid] + part[1][1][tid];
        float gg = pr[1024 + jj]   + part[0][2][tid] + part[1][2][tid];
        float go = pr[1536 + jj]   + part[0][3][tid] + part[1][3][tid];
        float cprev = (t == 0) ? 0.f : cstate[b * 512 + jj];
        float si = 1.f / (1.f + expf(-gi));
        float sf = 1.f / (1.f + expf(-gf));
        float so = 1.f / (1.f + expf(-go));
        float cn = sf * cprev + si * tanhf(gg);
        cstate[b * 512 + jj] = cn;
        hseq[(size_t)(b * L_ + t) * C_ + jj] = so * tanhf(cn);
    }
}

// ======================= banded attention (radius 50) =======================
__global__ __launch_bounds__(128) void attn_kernel(const float* __restrict__ q,
                                                   const float* __restrict__ k,
                                                   const float* __restrict__ cnt,
                                                   const float* __restrict__ rel,
                                                   float* __restrict__ out)
{
    int t = blockIdx.x, h = blockIdx.y, b = blockIdx.z;
    int s_lo = max(0, t - R_), s_hi = min(L_ - 1, t + R_);
    int W = s_hi - s_lo + 1;
    int tid = threadIdx.x;

    __shared__ float qrow[64];
    __shared__ float dots[104];
    __shared__ float red[128];

    const float* qp = q + ((size_t)(b * L_ + t) * C_ + h * D_);
    if (tid < 64) qrow[tid] = qp[tid];
    __syncthreads();

    if (tid < W) {
        int s = s_lo + tid;
        const float* kp = k + ((size_t)(b * L_ + s) * C_ + h * D_);
        const float* rp = rel + (R_ + t - s) * D_;
        float acc = 0.f;
#pragma unroll 8
        for (int d = 0; d < 64; ++d)
            acc += qrow[d] * (kp[d] + 0.3f * rp[d]);
        dots[tid] = acc;
    }
    __syncthreads();

    // stable softmax over window
    red[tid] = (tid < W) ? dots[tid] : -INFINITY;
    __syncthreads();
    for (int s = 64; s > 0; s >>= 1) {
        if (tid < s) red[tid] = fmaxf(red[tid], red[tid + s]);
        __syncthreads();
    }
    float mx = red[0];
    __syncthreads();
    float e = 0.f;
    if (tid < W) { e = expf(dots[tid] - mx); dots[tid] = e; }
    red[tid] = e;
    __syncthreads();
    for (int s = 64; s > 0; s >>= 1) {
        if (tid < s) red[tid] += red[tid + s];
        __syncthreads();
    }
    float inv = 1.f / red[0];
    if (tid < W) dots[tid] *= inv;
    __syncthreads();

    if (tid < 64) {
        float acc = 0.f;
        const float* cb = cnt + ((size_t)(b * L_ + s_lo) * C_ + h * D_ + tid);
        const float* rb = rel + (R_ + t - s_lo) * D_ + tid;
        for (int i = 0; i < W; ++i)
            acc += dots[i] * (cb[(size_t)i * C_] + 0.3f * rb[-i * D_]);
        out[(size_t)(b * L_ + t) * C_ + h * D_ + tid] = acc;
    }
}

// ======================= BatchNorm training stats =======================
__global__ __launch_bounds__(256) void bn_stats(const float* __restrict__ fcout, float* __restrict__ stats)
{
    int o = blockIdx.x;
    int tid = threadIdx.x;
    float s = 0.f, ss = 0.f;
    for (int m = tid; m < M_; m += 256) {
        float v = fcout[(size_t)m * 512 + o];
        s += v; ss += v * v;
    }
    __shared__ float rs[256], rq[256];
    rs[tid] = s; rq[tid] = ss;
    __syncthreads();
    for (int k = 128; k > 0; k >>= 1) {
        if (tid < k) { rs[tid] += rs[tid + k]; rq[tid] += rq[tid + k]; }
        __syncthreads();
    }
    if (tid == 0) {
        float mean = rs[0] / (float)M_;
        float var = rq[0] / (float)M_ - mean * mean;
        stats[o] = mean;
        stats[512 + o] = rsqrtf(fmaxf(var, 0.f) + 1e-5f);
    }
}

// ======================= BN apply + ReLU + scale + residual (in-place on h1seq) =======================
__global__ __launch_bounds__(256) void bn_apply(const float* __restrict__ fcout,
                                                const float* __restrict__ stats,
                                                const float* __restrict__ bng, const float* __restrict__ bnb,
                                                const float* __restrict__ ascl,
                                                float* __restrict__ xres)
{
    int idx = blockIdx.x * 256 + threadIdx.x;
    if (idx >= M_ * 512) return;
    int c = idx & 511;
    float v = (fcout[idx] - stats[c]) * stats[512 + c] * bng[c] + bnb[c];
    v = fmaxf(v, 0.f) * ascl[c];
    xres[idx] += v;
}

// ======================= host launch =======================
extern "C" void kernel_launch(void* const* d_in, const int* in_sizes, int n_in,
                              void* d_out, int out_size, void* d_ws, size_t ws_size,
                              hipStream_t stream)
{
    const float* meg  = (const float*)d_in[0];
    const float* w1   = (const float*)d_in[1];
    const float* b1   = (const float*)d_in[2];
    const float* w2   = (const float*)d_in[3];
    const float* b2   = (const float*)d_in[4];
    const float* semb = (const float*)d_in[5];
    const float* Wih0 = (const float*)d_in[6];
    const float2* Whh0 = (const float2*)d_in[7];
    const float* bih0 = (const float*)d_in[8];
    const float* bhh0 = (const float*)d_in[9];
    const float* Wih1 = (const float*)d_in[10];
    const float2* Whh1 = (const float2*)d_in[11];
    const float* bih1 = (const float*)d_in[12];
    const float* bhh1 = (const float*)d_in[13];
    const float* qw   = (const float*)d_in[14];
    const float* qb   = (const float*)d_in[15];
    const float* kw   = (const float*)d_in[16];
    const float* kb   = (const float*)d_in[17];
    const float* cw   = (const float*)d_in[18];
    const float* cbi  = (const float*)d_in[19];
    const float* rel  = (const float*)d_in[20];
    const float* fcw  = (const float*)d_in[21];
    const float* fcb  = (const float*)d_in[22];
    const float* bng  = (const float*)d_in[23];
    const float* bnb  = (const float*)d_in[24];
    const float* ascl = (const float*)d_in[25];
    const float* outw = (const float*)d_in[26];
    const float* outb = (const float*)d_in[27];
    const int* subj = (const int*)d_in[28];
    float* out = (float*)d_out;

    float* ws = (float*)d_ws;
    // arena (float offsets)
    float* x1    = ws + 0;          // [8200][512]   -> 4,198,400
    float* x2bt  = ws + 4198400;    // [4104][576]   -> 6,562,304
    float* pre   = ws + 6562304;    // [4104][2048]  -> 14,967,296
    float* h0    = ws + 14967296;   // [4104][512]   -> 17,068,544
    float* h1    = ws + 17068544;   // [4104][512]   -> 19,169,792
    float* cst   = ws + 19169792;   // [8][512]      -> 19,173,888
    float2* W2_0 = (float2*)(ws + 19173888);  // 524,288 float2 -> 20,222,464
    float2* W2_1 = (float2*)(ws + 20222464);  //               -> 21,271,040
    // overlays (dead buffers reused):
    float* qb_f  = ws + 0;          // q  [4104][512] over x1
    float* kb_f  = ws + 2101248;    // k
    float* cb_f  = ws + 4202496;    // cnt (spills into dead x2bt region)
    float* attno = ws + 6562304;    // over pre (dead after LSTM layer 1)
    float* fco   = ws + 8663552;
    float* stats = ws + 10764800;   // 1024 floats

    auto gemm = [&](const void* A, const float* Bw, const float* bi1, const float* bi2,
                    float* Cf, int Msz, int Nsz, int Ksz,
                    int lda, int ldc, int amode, int cmode, int relu) {
        dim3 g((Msz + 63) / 64, Nsz / 64);
        gemm_kernel<<<g, 256, 0, stream>>>(A, Bw, bi1, bi2, Cf,
                                           Msz, Nsz, Ksz, lda, ldc, amode, cmode, relu);
    };

    // pack recurrent weights
    pack_whh<<<dim3(64, 8), 256, 0, stream>>>(Whh0, W2_0);
    pack_whh<<<dim3(64, 8), 256, 0, stream>>>(Whh1, W2_1);

    // conv1 (im2col from meg) -> x1 [b*1025+t][512], relu
    gemm(meg, w1, b1, nullptr, x1, M1_, 512, K1_, 0, 512, 2, 0, 1);
    // conv2 (im2col from x1) -> x2bt [b*513+t][576] cols 0..511, relu
    gemm(x1, w2, b2, nullptr, x2bt, M_, 512, 2048, 0, CE_, 3, 0, 1);
    // subject embedding -> cols 512..575
    emb_kernel<<<(M_ * 64 + 255) / 256, 256, 0, stream>>>(semb, subj, x2bt);

    // LSTM layer 0
    gemm(x2bt, Wih0, bih0, bhh0, pre, M_, 2048, CE_, CE_, 2048, 0, 0, 0);
    for (int t = 0; t < L_; ++t)
        lstm_step<<<128, 256, 0, stream>>>(pre, W2_0, h0, cst, t);
    // LSTM layer 1
    gemm(h0, Wih1, bih1, bhh1, pre, M_, 2048, 512, 512, 2048, 0, 0, 0);
    for (int t = 0; t < L_; ++t)
        lstm_step<<<128, 256, 0, stream>>>(pre, W2_1, h1, cst, t);

    // attention projections
    gemm(h1, qw, qb, nullptr, qb_f, M_, 512, 512, 512, 512, 0, 0, 0);
    gemm(h1, kw, kb, nullptr, kb_f, M_, 512, 512, 512, 512, 0, 0, 0);
    gemm(h1, cw, cbi, nullptr, cb_f, M_, 512, 512, 512, 512, 0, 0, 0);

    attn_kernel<<<dim3(L_, H_, B_), 128, 0, stream>>>(qb_f, kb_f, cb_f, rel, attno);

    // fc + BN(train) + relu*scale + residual into h1
    gemm(attno, fcw, fcb, nullptr, fco, M_, 512, 512, 512, 512, 0, 0, 0);
    bn_stats<<<512, 256, 0, stream>>>(fco, stats);
    bn_apply<<<(M_ * 512 + 255) / 256, 256, 0, stream>>>(fco, stats, bng, bnb, ascl, h1);

    // final projection -> d_out [b][128][t] fp32
    gemm(h1, outw, outb, nullptr, out, M_, 128, 512, 512, 0, 0, 1, 0);
}